// Round 1
// baseline (939.142 us; speedup 1.0000x reference)
//
#include <hip/hip_runtime.h>

// Problem constants (B, CQ, CR, HID, H, W) = (8, 1024, 512, 256, 48, 48)
#define BB   8
#define PP   2304      // H*W
#define CQD  1024
#define CRD  512
#define HIDD 256

typedef float f32x4 __attribute__((ext_vector_type(4)));
typedef __bf16 bf16x8 __attribute__((ext_vector_type(8)));
typedef unsigned short u16x8 __attribute__((ext_vector_type(8)));
typedef unsigned short u16x4 __attribute__((ext_vector_type(4)));

__device__ __forceinline__ unsigned short f2bf(float f) {
  unsigned int u = __float_as_uint(f);
  u += 0x7fffu + ((u >> 16) & 1u);   // RNE on magnitude
  return (unsigned short)(u >> 16);
}
__device__ __forceinline__ float bf2f(unsigned short h) {
  return __uint_as_float(((unsigned int)h) << 16);
}
__device__ __forceinline__ bf16x8 load_bf8(const unsigned short* p) {
  return *(const bf16x8*)p;
}

#define MFMA16(a, b, c) __builtin_amdgcn_mfma_f32_16x16x32_bf16((a), (b), (c), 0, 0, 0)

// ---------------------------------------------------------------------------
// Projection: Out[b][p][o] = sum_c W[o][c] * X[b][c][p] + bias[o]
// Computed as D[m=o][n=p] tiles; A = W (hi/lo), B = X staged hi/lo in LDS.
// bf16x3 split product => ~fp32-quality logit path.
// Output stored as hi/lo bf16 pair, layout [b][p][HID] (hid contiguous).
// ---------------------------------------------------------------------------
template <int C>
__global__ __launch_bounds__(256) void proj_kernel(
    const float* __restrict__ X, const float* __restrict__ W,
    const float* __restrict__ bias,
    unsigned short* __restrict__ Oh, unsigned short* __restrict__ Ol) {
  const int b = blockIdx.z;
  const int p0 = blockIdx.y * 64;
  const int o0 = blockIdx.x * 64;
  const int tid = threadIdx.x;
  const int lane = tid & 63;
  const int wave = tid >> 6;
  const int wm = wave & 1;   // o direction (2 x 32)
  const int wn = wave >> 1;  // p direction (2 x 32)
  const int l15 = lane & 15;
  const int quad = lane >> 4;

  __shared__ unsigned short Xh[64][40];  // [p][c] hi, padded
  __shared__ unsigned short Xl[64][40];  // [p][c] lo

  f32x4 acc[2][2] = {};

  const float* Xb = X + (size_t)b * C * PP;
  const int cc = tid >> 3;         // 0..31 channel row within k-slab
  const int ppo = (tid & 7) * 8;   // 0..56 pixel offset

  for (int c0 = 0; c0 < C; c0 += 32) {
    // stage X[c0..c0+32)[p0..p0+64) -> LDS transposed, split hi/lo
    const float* src = Xb + (size_t)(c0 + cc) * PP + p0 + ppo;
    float4 v0 = *(const float4*)(src);
    float4 v1 = *(const float4*)(src + 4);
    float vv[8] = {v0.x, v0.y, v0.z, v0.w, v1.x, v1.y, v1.z, v1.w};
#pragma unroll
    for (int j = 0; j < 8; ++j) {
      unsigned short h = f2bf(vv[j]);
      Xh[ppo + j][cc] = h;
      Xl[ppo + j][cc] = f2bf(vv[j] - bf2f(h));
    }
    __syncthreads();

    // A fragments from W (fp32 global, L1/L2 resident), split hi/lo
    bf16x8 wh[2], wl[2];
#pragma unroll
    for (int mt = 0; mt < 2; ++mt) {
      const float* wsrc =
          W + (size_t)(o0 + wm * 32 + mt * 16 + l15) * C + c0 + quad * 8;
      float4 a0 = *(const float4*)(wsrc);
      float4 a1 = *(const float4*)(wsrc + 4);
      float av[8] = {a0.x, a0.y, a0.z, a0.w, a1.x, a1.y, a1.z, a1.w};
      u16x8 hh, ll;
#pragma unroll
      for (int j = 0; j < 8; ++j) {
        unsigned short h = f2bf(av[j]);
        hh[j] = h;
        ll[j] = f2bf(av[j] - bf2f(h));
      }
      wh[mt] = __builtin_bit_cast(bf16x8, hh);
      wl[mt] = __builtin_bit_cast(bf16x8, ll);
    }

#pragma unroll
    for (int nt = 0; nt < 2; ++nt) {
      const int pr = wn * 32 + nt * 16 + l15;
      bf16x8 xh = load_bf8(&Xh[pr][quad * 8]);
      bf16x8 xl = load_bf8(&Xl[pr][quad * 8]);
#pragma unroll
      for (int mt = 0; mt < 2; ++mt) {
        acc[mt][nt] = MFMA16(wh[mt], xh, acc[mt][nt]);
        acc[mt][nt] = MFMA16(wl[mt], xh, acc[mt][nt]);
        acc[mt][nt] = MFMA16(wh[mt], xl, acc[mt][nt]);
      }
    }
    __syncthreads();
  }

  // epilogue: add bias, split result hi/lo, store [p][o] rows (o contiguous)
#pragma unroll
  for (int mt = 0; mt < 2; ++mt) {
    const int ob = o0 + wm * 32 + mt * 16 + quad * 4;
#pragma unroll
    for (int nt = 0; nt < 2; ++nt) {
      const int p = p0 + wn * 32 + nt * 16 + l15;
      u16x4 hs, ls;
#pragma unroll
      for (int r = 0; r < 4; ++r) {
        float v = acc[mt][nt][r] + bias[ob + r];
        unsigned short h = f2bf(v);
        hs[r] = h;
        ls[r] = f2bf(v - bf2f(h));
      }
      const size_t base = ((size_t)b * PP + p) * HIDD + ob;
      *(u16x4*)(Oh + base) = hs;
      *(u16x4*)(Ol + base) = ls;
    }
  }
}

// ---------------------------------------------------------------------------
// V cast: reference_features fp32 [b][c][p] -> bf16, same layout
// ---------------------------------------------------------------------------
__global__ void cast_v_kernel(const float* __restrict__ X,
                              unsigned short* __restrict__ V) {
  const size_t i = ((size_t)blockIdx.x * 256 + threadIdx.x) * 4;
  float4 v = *(const float4*)(X + i);
  u16x4 o;
  o[0] = f2bf(v.x);
  o[1] = f2bf(v.y);
  o[2] = f2bf(v.z);
  o[3] = f2bf(v.w);
  *(u16x4*)(V + i) = o;
}

// ---------------------------------------------------------------------------
// Fused flash attention over pixels.
// Per WG: 32 q-pixels, loop over 64-key tiles.
//   S  = Qh*Kh + Qh*Kl + Ql*Kh  (fp32 accum, split-bf16 logits)
//   online softmax (m, l, alpha in LDS), P -> bf16 in LDS
//   O += P * V^T  (wave w owns value-channel slice [128w, 128w+128))
// ---------------------------------------------------------------------------
__global__ __launch_bounds__(256) void attn_kernel(
    const unsigned short* __restrict__ Qh, const unsigned short* __restrict__ Ql,
    const unsigned short* __restrict__ Kh, const unsigned short* __restrict__ Kl,
    const unsigned short* __restrict__ Vb, float* __restrict__ out) {
  const int b = blockIdx.y;
  const int q0 = blockIdx.x * 32;
  const int tid = threadIdx.x;
  const int lane = tid & 63;
  const int wave = tid >> 6;
  const int l15 = lane & 15;
  const int quad = lane >> 4;

  __shared__ float S_lds[32][72];
  __shared__ unsigned short P_lds[32][72];
  __shared__ float m_state[32], l_state[32], a_state[32];

  if (tid < 32) {
    m_state[tid] = -3.0e38f;
    l_state[tid] = 0.f;
  }

  // Preload Q fragments (loop-invariant): A[m=q][k=hid]
  bf16x8 qh[2][8], ql[2][8];
#pragma unroll
  for (int mt = 0; mt < 2; ++mt) {
    const size_t rowb =
        ((size_t)b * PP + q0 + mt * 16 + l15) * HIDD + quad * 8;
#pragma unroll
    for (int ks = 0; ks < 8; ++ks) {
      qh[mt][ks] = load_bf8(Qh + rowb + ks * 32);
      ql[mt][ks] = load_bf8(Ql + rowb + ks * 32);
    }
  }

  f32x4 o_acc[2][8] = {};

  const int srow = tid >> 3;        // softmax row 0..31
  const int scol = (tid & 7) * 8;   // softmax col base

  __syncthreads();

  for (int kt = 0; kt < PP; kt += 64) {
    // ---- S phase: wave handles key slice [kt + 16*wave, +16) ----
    f32x4 s_acc[2] = {};
    const size_t krow =
        ((size_t)b * PP + kt + wave * 16 + l15) * HIDD + quad * 8;
#pragma unroll
    for (int ks = 0; ks < 8; ++ks) {
      bf16x8 bh = load_bf8(Kh + krow + ks * 32);
      bf16x8 bl = load_bf8(Kl + krow + ks * 32);
#pragma unroll
      for (int mt = 0; mt < 2; ++mt) {
        s_acc[mt] = MFMA16(qh[mt][ks], bh, s_acc[mt]);
        s_acc[mt] = MFMA16(ql[mt][ks], bh, s_acc[mt]);
        s_acc[mt] = MFMA16(qh[mt][ks], bl, s_acc[mt]);
      }
    }
#pragma unroll
    for (int mt = 0; mt < 2; ++mt)
#pragma unroll
      for (int r = 0; r < 4; ++r)
        S_lds[mt * 16 + quad * 4 + r][wave * 16 + l15] = s_acc[mt][r];
    __syncthreads();

    // ---- online softmax: 8 threads per q-row, 8 cols each ----
    {
      float v[8];
#pragma unroll
      for (int j = 0; j < 8; ++j) v[j] = S_lds[srow][scol + j];
      float mx = v[0];
#pragma unroll
      for (int j = 1; j < 8; ++j) mx = fmaxf(mx, v[j]);
      mx = fmaxf(mx, __shfl_xor(mx, 1));
      mx = fmaxf(mx, __shfl_xor(mx, 2));
      mx = fmaxf(mx, __shfl_xor(mx, 4));
      const float mold = m_state[srow];
      const float mnew = fmaxf(mold, mx);
      const float alpha = __expf(mold - mnew);  // 0 on first tile
      float ssum = 0.f;
#pragma unroll
      for (int j = 0; j < 8; ++j) {
        float p = __expf(v[j] - mnew);
        ssum += p;
        P_lds[srow][scol + j] = f2bf(p);
      }
      ssum += __shfl_xor(ssum, 1);
      ssum += __shfl_xor(ssum, 2);
      ssum += __shfl_xor(ssum, 4);
      if ((tid & 7) == 0) {
        m_state[srow] = mnew;
        l_state[srow] = l_state[srow] * alpha + ssum;
        a_state[srow] = alpha;
      }
    }
    __syncthreads();

    // ---- rescale O by alpha ----
    float alph[2][4];
#pragma unroll
    for (int mt = 0; mt < 2; ++mt)
#pragma unroll
      for (int r = 0; r < 4; ++r)
        alph[mt][r] = a_state[mt * 16 + quad * 4 + r];
#pragma unroll
    for (int mt = 0; mt < 2; ++mt)
#pragma unroll
      for (int nt = 0; nt < 8; ++nt)
#pragma unroll
        for (int r = 0; r < 4; ++r) o_acc[mt][nt][r] *= alph[mt][r];

    // ---- PV phase: A = P (from LDS), B = V (global, [c][p] contiguous) ----
#pragma unroll
    for (int ks = 0; ks < 2; ++ks) {
      bf16x8 pa[2];
#pragma unroll
      for (int mt = 0; mt < 2; ++mt)
        pa[mt] = load_bf8(&P_lds[mt * 16 + l15][ks * 32 + quad * 8]);
#pragma unroll
      for (int nt = 0; nt < 8; ++nt) {
        const int c = wave * 128 + nt * 16 + l15;
        bf16x8 vb = load_bf8(Vb + ((size_t)b * CRD + c) * PP + kt +
                             ks * 32 + quad * 8);
#pragma unroll
        for (int mt = 0; mt < 2; ++mt)
          o_acc[mt][nt] = MFMA16(pa[mt], vb, o_acc[mt][nt]);
      }
    }
    __syncthreads();  // protect S_lds/P_lds/a_state reuse next tile
  }

  // ---- epilogue: divide by l, store fp32 [b][c][p] ----
  float rl[2][4];
#pragma unroll
  for (int mt = 0; mt < 2; ++mt)
#pragma unroll
    for (int r = 0; r < 4; ++r)
      rl[mt][r] = 1.f / l_state[mt * 16 + quad * 4 + r];

#pragma unroll
  for (int mt = 0; mt < 2; ++mt)
#pragma unroll
    for (int nt = 0; nt < 8; ++nt) {
      const int c = wave * 128 + nt * 16 + l15;
      f32x4 v = o_acc[mt][nt];
#pragma unroll
      for (int r = 0; r < 4; ++r) v[r] *= rl[mt][r];
      *(f32x4*)(out + ((size_t)b * CRD + c) * PP + q0 + mt * 16 + quad * 4) = v;
    }
}

// ---------------------------------------------------------------------------
extern "C" void kernel_launch(void* const* d_in, const int* in_sizes, int n_in,
                              void* d_out, int out_size, void* d_ws,
                              size_t ws_size, hipStream_t stream) {
  (void)in_sizes;
  (void)n_in;
  (void)out_size;
  (void)ws_size;

  const float* Xq = (const float*)d_in[0];  // [8][1024][2304]
  const float* Xr = (const float*)d_in[1];  // [8][512][2304]
  const float* Wq = (const float*)d_in[2];  // [256][1024]
  const float* bq = (const float*)d_in[3];  // [256]
  const float* Wk = (const float*)d_in[4];  // [256][512]
  const float* bk = (const float*)d_in[5];  // [256]
  float* out = (float*)d_out;               // [8][512][2304]

  // workspace: Qh,Ql,Kh,Kl [8][2304][256] bf16 + Vb [8][512][2304] bf16
  //   = 4*9.44 MB + 18.9 MB = 56.6 MB
  const size_t nQK = (size_t)BB * PP * HIDD;
  unsigned short* Qh = (unsigned short*)d_ws;
  unsigned short* Ql = Qh + nQK;
  unsigned short* Kh = Ql + nQK;
  unsigned short* Kl = Kh + nQK;
  unsigned short* Vb = Kl + nQK;

  proj_kernel<CQD><<<dim3(4, 36, BB), 256, 0, stream>>>(Xq, Wq, bq, Qh, Ql);
  proj_kernel<CRD><<<dim3(4, 36, BB), 256, 0, stream>>>(Xr, Wk, bk, Kh, Kl);
  cast_v_kernel<<<dim3((BB * CRD * PP) / (256 * 4)), 256, 0, stream>>>(Xr, Vb);
  attn_kernel<<<dim3(PP / 32, BB), 256, 0, stream>>>(Qh, Ql, Kh, Kl, Vb, out);
}